// Round 1
// baseline (127.827 us; speedup 1.0000x reference)
//
#include <hip/hip_runtime.h>

typedef __attribute__((ext_vector_type(8))) __bf16 bf16x8;
typedef __attribute__((ext_vector_type(4))) float f32x4;

// ---------------------------------------------------------------------------
// Kernel 1: one graph per block. Fused dual-GEMM (states+gates) -> softmax ->
// gating -> column-sum -> mean.  x tiles (64 nodes) staged f32->bf16 in LDS.
// Wave w owns output cols [32w, 32w+32) of BOTH states and gates.
// ---------------------------------------------------------------------------
__global__ __launch_bounds__(256, 2) void gnn_agg(
    const float* __restrict__ x, const int* __restrict__ batch,
    const float* __restrict__ Wlin, const float* __restrict__ blin,
    const float* __restrict__ Wgate, const float* __restrict__ bgate,
    float* __restrict__ meanOut, int nNodes)
{
    __shared__ __bf16 ldsA[64 * 128];   // 16 KB, XOR-swizzled
    __shared__ float  ldsPS[64][4];     // per-row partial exp-sums per wave

    const int tid  = threadIdx.x;
    const int lane = tid & 63;
    const int w    = tid >> 6;    // wave 0..3
    const int l15  = lane & 15;
    const int lg   = lane >> 4;   // 0..3
    const int g    = blockIdx.x;

    // --- binary search graph range in sorted batch (uniform across threads)
    int lo = 0, hi = nNodes;
    while (lo < hi) { int mid = (lo + hi) >> 1; if (batch[mid] < g) lo = mid + 1; else hi = mid; }
    const int start = lo;
    hi = nNodes;
    while (lo < hi) { int mid = (lo + hi) >> 1; if (batch[mid] < g + 1) lo = mid + 1; else hi = mid; }
    const int end   = lo;
    const int count = end - start;

    // --- load W fragments (B operand) into registers, f32 -> bf16
    // bfrag[wt][jt][kk]: wt 0=lin 1=gate; col = w*32 + jt*16 + l15; k = kk*32 + lg*8 + i
    bf16x8 bfrag[2][2][4];
#pragma unroll
    for (int wt = 0; wt < 2; ++wt) {
        const float* W = wt ? Wgate : Wlin;
#pragma unroll
        for (int jt = 0; jt < 2; ++jt) {
            const float* Wp = W + (size_t)(w * 32 + jt * 16 + l15) * 128 + lg * 8;
#pragma unroll
            for (int kk = 0; kk < 4; ++kk) {
                f32x4 u0 = *(const f32x4*)(Wp + kk * 32);
                f32x4 u1 = *(const f32x4*)(Wp + kk * 32 + 4);
                bf16x8 t;
                t[0] = (__bf16)u0.x; t[1] = (__bf16)u0.y; t[2] = (__bf16)u0.z; t[3] = (__bf16)u0.w;
                t[4] = (__bf16)u1.x; t[5] = (__bf16)u1.y; t[6] = (__bf16)u1.z; t[7] = (__bf16)u1.w;
                bfrag[wt][jt][kk] = t;
            }
        }
    }
    float bl[2], bg[2];
#pragma unroll
    for (int jt = 0; jt < 2; ++jt) {
        bl[jt] = blin[w * 32 + jt * 16 + l15];
        bg[jt] = bgate[w * 32 + jt * 16 + l15];
    }

    float accG0 = 0.f, accG1 = 0.f;
    const int nt = (count + 63) >> 6;

    // register prefetch buffer: 4 groups x 8 floats
    f32x4 pf[4][2];

    auto issue_loads = [&](int t) {
        const int base = start + (t << 6);
#pragma unroll
        for (int i = 0; i < 4; ++i) {
            const int G = tid + (i << 8);
            const int row = G >> 4, kg = G & 15;
            const int node = base + row;
            if (node < end) {
                const f32x4* p = (const f32x4*)(x + (size_t)node * 128 + kg * 8);
                pf[i][0] = p[0];
                pf[i][1] = p[1];
            } else {
                pf[i][0] = (f32x4)0.f;
                pf[i][1] = (f32x4)0.f;
            }
        }
    };

    if (nt > 0) issue_loads(0);

    for (int t = 0; t < nt; ++t) {
        // ---- stage prefetched tile into LDS (bf16, XOR swizzle on 16B units)
#pragma unroll
        for (int i = 0; i < 4; ++i) {
            const int G = tid + (i << 8);
            const int row = G >> 4, kg = G & 15;
            bf16x8 v;
            v[0] = (__bf16)pf[i][0].x; v[1] = (__bf16)pf[i][0].y;
            v[2] = (__bf16)pf[i][0].z; v[3] = (__bf16)pf[i][0].w;
            v[4] = (__bf16)pf[i][1].x; v[5] = (__bf16)pf[i][1].y;
            v[6] = (__bf16)pf[i][1].z; v[7] = (__bf16)pf[i][1].w;
            const int off = (row * 256 + kg * 16) ^ ((row & 7) << 4);
            *(bf16x8*)((char*)ldsA + off) = v;
        }
        if (t + 1 < nt) issue_loads(t + 1);
        __syncthreads();

        // ---- GEMM: acc[r16][j], j = {0,1}: states jt, {2,3}: gates jt
        f32x4 acc[4][4];
#pragma unroll
        for (int a = 0; a < 4; ++a)
#pragma unroll
            for (int b = 0; b < 4; ++b) acc[a][b] = (f32x4)0.f;

#pragma unroll
        for (int kk = 0; kk < 4; ++kk) {
            bf16x8 afrag[4];
#pragma unroll
            for (int r16 = 0; r16 < 4; ++r16) {
                const int row = r16 * 16 + l15;
                const int off = (row * 256 + kk * 64 + lg * 16) ^ ((row & 7) << 4);
                afrag[r16] = *(const bf16x8*)((const char*)ldsA + off);
            }
#pragma unroll
            for (int r16 = 0; r16 < 4; ++r16) {
#pragma unroll
                for (int j = 0; j < 4; ++j) {
                    acc[r16][j] = __builtin_amdgcn_mfma_f32_16x16x32_bf16(
                        afrag[r16], bfrag[j >> 1][j & 1][kk], acc[r16][j], 0, 0, 0);
                }
            }
        }

        // ---- epilogue: softmax over gate cols (128) without max-subtract
        // D layout: row = r16*16 + lg*4 + r, col = w*32 + jt*16 + l15
#pragma unroll
        for (int r16 = 0; r16 < 4; ++r16) {
#pragma unroll
            for (int r = 0; r < 4; ++r) {
                float e0 = __expf(acc[r16][2][r] + bg[0]);
                float e1 = __expf(acc[r16][3][r] + bg[1]);
                float p = e0 + e1;
                p += __shfl_xor(p, 1);
                p += __shfl_xor(p, 2);
                p += __shfl_xor(p, 4);
                p += __shfl_xor(p, 8);
                if (l15 == 0) ldsPS[r16 * 16 + lg * 4 + r][w] = p;
            }
        }
        __syncthreads();

        const int tbase = start + (t << 6);
        float v0 = 0.f, v1 = 0.f;
#pragma unroll
        for (int r16 = 0; r16 < 4; ++r16) {
#pragma unroll
            for (int r = 0; r < 4; ++r) {
                const int row = r16 * 16 + lg * 4 + r;
                f32x4 q = *(f32x4*)&ldsPS[row][0];
                float inv = 1.0f / (q.x + q.y + q.z + q.w);
                float e0 = __expf(acc[r16][2][r] + bg[0]);
                float e1 = __expf(acc[r16][3][r] + bg[1]);
                float g0 = (acc[r16][0][r] + bl[0]) * e0 * inv;
                float g1 = (acc[r16][1][r] + bl[1]) * e1 * inv;
                if (tbase + row >= end) { g0 = 0.f; g1 = 0.f; }
                v0 += g0;
                v1 += g1;
            }
        }
        v0 += __shfl_xor(v0, 16); v0 += __shfl_xor(v0, 32);
        v1 += __shfl_xor(v1, 16); v1 += __shfl_xor(v1, 32);
        accG0 += v0;
        accG1 += v1;
        __syncthreads();
    }

    // ---- write mean for this graph
    const float invC = 1.0f / (float)(count > 0 ? count : 1);
    if (lane < 16) {
        meanOut[g * 128 + w * 32 + l15]      = accG0 * invC;
        meanOut[g * 128 + w * 32 + 16 + l15] = accG1 * invC;
    }
}

// ---------------------------------------------------------------------------
// Kernel 2: out[g][c] = b_final[c] + sum_k mean[g][k] * W_final[c][k]
// ---------------------------------------------------------------------------
__global__ __launch_bounds__(128) void final_mm(
    const float* __restrict__ mean, const float* __restrict__ Wf,
    const float* __restrict__ bf, float* __restrict__ out)
{
    const int g = blockIdx.x, c = threadIdx.x;
    __shared__ float m[128];
    m[c] = mean[g * 128 + c];
    __syncthreads();
    float acc = bf[c];
    const f32x4* wr = (const f32x4*)(Wf + (size_t)c * 128);
#pragma unroll
    for (int k = 0; k < 32; ++k) {
        f32x4 wv = wr[k];
        acc += m[4 * k] * wv.x + m[4 * k + 1] * wv.y + m[4 * k + 2] * wv.z + m[4 * k + 3] * wv.w;
    }
    out[g * 128 + c] = acc;
}

extern "C" void kernel_launch(void* const* d_in, const int* in_sizes, int n_in,
                              void* d_out, int out_size, void* d_ws, size_t ws_size,
                              hipStream_t stream)
{
    const float* x     = (const float*)d_in[0];
    const int*   batch = (const int*)d_in[1];
    const float* Wlin  = (const float*)d_in[2];
    const float* blin  = (const float*)d_in[3];
    const float* Wgate = (const float*)d_in[4];
    const float* bgate = (const float*)d_in[5];
    const float* Wfin  = (const float*)d_in[6];
    const float* bfin  = (const float*)d_in[7];
    float* out     = (float*)d_out;
    float* meanBuf = (float*)d_ws;

    const int nNodes  = in_sizes[1];
    const int nGraphs = out_size / 128;

    gnn_agg<<<nGraphs, 256, 0, stream>>>(x, batch, Wlin, blin, Wgate, bgate, meanBuf, nNodes);
    final_mm<<<nGraphs, 128, 0, stream>>>(meanBuf, Wfin, bfin, out);
}